// Round 6
// baseline (399.389 us; speedup 1.0000x reference)
//
#include <hip/hip_runtime.h>
#include <hip/hip_bf16.h>
#include <math.h>

// Problem constants (B,S,H,NH,HS) = (4,2048,1024,16,64)
#define B_  4
#define S_  2048
#define H_  1024
#define NH_ 16
#define HS_ 64

typedef __attribute__((ext_vector_type(8))) short bf16x8;
typedef __attribute__((ext_vector_type(4))) float f32x4;

__device__ __forceinline__ short f2bf(float f) {
    // round-to-nearest-even fp32 -> bf16 (finite inputs only)
    unsigned u = __builtin_bit_cast(unsigned, f);
    u += 0x7FFFu + ((u >> 16) & 1u);
    return (short)(u >> 16);
}

typedef __attribute__((address_space(3))) void lds_void;
typedef const __attribute__((address_space(1))) void g_void;
__device__ __forceinline__ void gl_lds16(const void* g, void* l) {
    __builtin_amdgcn_global_load_lds((g_void*)g, (lds_void*)l, 16, 0, 0);
}

// ---------------------------------------------------------------------------
// Fused fp32 -> bf16 convert for all 7 tensors. blockIdx.y selects tensor.
// ---------------------------------------------------------------------------
__global__ __launch_bounds__(256) void cvt_all_k(
    const float* __restrict__ a0, const float* __restrict__ a1,
    const float* __restrict__ a2, const float* __restrict__ w0,
    const float* __restrict__ w1, const float* __restrict__ w2,
    const float* __restrict__ w3,
    short* o0, short* o1, short* o2, short* o3, short* o4, short* o5, short* o6)
{
    const int y = blockIdx.y;
    const float* ins[7]  = {a0, a1, a2, w0, w1, w2, w3};
    short*       outs[7] = {o0, o1, o2, o3, o4, o5, o6};
    const int n8 = (y < 3) ? (int)((size_t)B_ * S_ * H_ / 8) : (int)((size_t)H_ * H_ / 8);
    const int i = blockIdx.x * 256 + threadIdx.x;
    if (i >= n8) return;
    const float4* p = (const float4*)ins[y] + (size_t)i * 2;
    float4 a = p[0], b = p[1];
    bf16x8 o;
    o[0] = f2bf(a.x); o[1] = f2bf(a.y); o[2] = f2bf(a.z); o[3] = f2bf(a.w);
    o[4] = f2bf(b.x); o[5] = f2bf(b.y); o[6] = f2bf(b.z); o[7] = f2bf(b.w);
    *(bf16x8*)(outs[y] + (size_t)i * 8) = o;
}

// ---------------------------------------------------------------------------
// Shared MFMA GEMM core: 128x128 tile, BK=64 (16 iters -> half the barrier
// drains of BK=32), 4 waves (2x2), wave = 64x64. K fixed at 1024.
// LDS 16 KB per matrix, staged with global_load_lds width=16.
// ---------------------------------------------------------------------------
__device__ __forceinline__ void gemm_core(
    const short* __restrict__ A, const short* __restrict__ W,
    int m0, int n0, short* As, short* Ws, f32x4 acc[4][4])
{
    const int tid  = threadIdx.x;
    const int w    = tid >> 6;
    const int lane = tid & 63;
    const int l15  = lane & 15;
    const int q4   = lane >> 4;
    const int wm   = w >> 1;
    const int wn   = w & 1;
    const int K    = 1024;

    const char* Abase = (const char*)A + (size_t)m0 * K * 2;
    const char* Wbase = (const char*)W + (size_t)n0 * K * 2;

    #pragma unroll
    for (int mi = 0; mi < 4; ++mi)
        #pragma unroll
        for (int ni = 0; ni < 4; ++ni)
            acc[mi][ni] = (f32x4){0.f, 0.f, 0.f, 0.f};

    for (int k0 = 0; k0 < K; k0 += 64) {
        __syncthreads();
        #pragma unroll
        for (int t = 0; t < 4; ++t) {
            const int ob = t * 4096 + w * 1024;   // wave-uniform LDS byte base
            const int o  = ob + lane * 16;
            const int row = o >> 7;               // 128 B per row (BK=64 bf16)
            const int kb  = o & 127;
            gl_lds16(Abase + (size_t)row * (K * 2) + k0 * 2 + kb, (char*)As + ob);
            gl_lds16(Wbase + (size_t)row * (K * 2) + k0 * 2 + kb, (char*)Ws + ob);
        }
        __syncthreads();

        #pragma unroll
        for (int kh = 0; kh < 2; ++kh) {
            bf16x8 af[4], bf[4];
            #pragma unroll
            for (int mi = 0; mi < 4; ++mi)
                af[mi] = *(const bf16x8*)(As + (wm * 64 + mi * 16 + l15) * 64 + kh * 32 + q4 * 8);
            #pragma unroll
            for (int ni = 0; ni < 4; ++ni)
                bf[ni] = *(const bf16x8*)(Ws + (wn * 64 + ni * 16 + l15) * 64 + kh * 32 + q4 * 8);
            #pragma unroll
            for (int mi = 0; mi < 4; ++mi)
                #pragma unroll
                for (int ni = 0; ni < 4; ++ni)
                    acc[mi][ni] = __builtin_amdgcn_mfma_f32_16x16x32_bf16(
                        af[mi], bf[ni], acc[mi][ni], 0, 0, 0);
        }
    }
}

// ---------------------------------------------------------------------------
// Fused projection GEMMs: z=0 -> q (scatter [B*NH,S,HS]), z=1 -> k (same),
// z=2 -> vT = Wv @ value^T (transpose-scatter [B*NH,HS,S]; bx/by roles swap).
// ---------------------------------------------------------------------------
__global__ __launch_bounds__(256) void gemm_proj_k(
    const short* __restrict__ Aq, const short* __restrict__ Wqb,
    const float* __restrict__ bq, short* __restrict__ qb,
    const short* __restrict__ Ak, const short* __restrict__ Wkb,
    const float* __restrict__ bk, short* __restrict__ kb,
    const short* __restrict__ Wvb, const short* __restrict__ Av,
    const float* __restrict__ bv, short* __restrict__ vtb)
{
    __shared__ short As[128 * 64];   // 16 KB
    __shared__ short Ws[128 * 64];   // 16 KB

    const int z = blockIdx.z;
    const short *A, *W; const float* bias; short* out;
    if (z == 0)      { A = Aq;  W = Wqb; bias = bq; out = qb;  }
    else if (z == 1) { A = Ak;  W = Wkb; bias = bk; out = kb;  }
    else             { A = Wvb; W = Av;  bias = bv; out = vtb; }
    const int m0 = (z == 2 ? blockIdx.y : blockIdx.x) * 128;
    const int n0 = (z == 2 ? blockIdx.x : blockIdx.y) * 128;

    f32x4 acc[4][4];
    gemm_core(A, W, m0, n0, As, Ws, acc);

    const int tid  = threadIdx.x;
    const int w    = tid >> 6;
    const int lane = tid & 63;
    const int l15  = lane & 15;
    const int q4   = lane >> 4;
    const int wm   = w >> 1;
    const int wn   = w & 1;

    #pragma unroll
    for (int mi = 0; mi < 4; ++mi) {
        #pragma unroll
        for (int r = 0; r < 4; ++r) {
            const int m = m0 + wm * 64 + mi * 16 + q4 * 4 + r;
            #pragma unroll
            for (int ni = 0; ni < 4; ++ni) {
                const int n = n0 + wn * 64 + ni * 16 + l15;
                const float v = acc[mi][ni][r] + bias[z == 2 ? m : n];
                if (z != 2) {
                    const int b = m >> 11, s = m & (S_ - 1);
                    const int h = n >> 6,  d = n & (HS_ - 1);
                    out[(((size_t)b * NH_ + h) * S_ + s) * HS_ + d] = f2bf(v);
                } else {
                    const int b = n >> 11, s = n & (S_ - 1);
                    const int h = m >> 6,  d = m & (HS_ - 1);
                    out[(((size_t)b * NH_ + h) * HS_ + d) * S_ + s] = f2bf(v);
                }
            }
        }
    }
}

// ---------------------------------------------------------------------------
// Output-projection GEMM: fp32 row-major out = ctx @ Wo^T + bo
// ---------------------------------------------------------------------------
__global__ __launch_bounds__(256) void gemm_out_k(
    const short* __restrict__ A, const short* __restrict__ W,
    const float* __restrict__ bias, float* __restrict__ Cout)
{
    __shared__ short As[128 * 64];
    __shared__ short Ws[128 * 64];
    const int m0 = blockIdx.x * 128;
    const int n0 = blockIdx.y * 128;

    f32x4 acc[4][4];
    gemm_core(A, W, m0, n0, As, Ws, acc);

    const int tid  = threadIdx.x;
    const int w    = tid >> 6;
    const int lane = tid & 63;
    const int l15  = lane & 15;
    const int q4   = lane >> 4;
    const int wm   = w >> 1;
    const int wn   = w & 1;

    #pragma unroll
    for (int mi = 0; mi < 4; ++mi)
        #pragma unroll
        for (int r = 0; r < 4; ++r) {
            const int m = m0 + wm * 64 + mi * 16 + q4 * 4 + r;
            #pragma unroll
            for (int ni = 0; ni < 4; ++ni) {
                const int n = n0 + wn * 64 + ni * 16 + l15;
                Cout[(size_t)m * H_ + n] = acc[mi][ni][r] + bias[n];
            }
        }
}

// ---------------------------------------------------------------------------
// MFMA flash attention, no-max softmax, work-balanced pairing {bx, 15-bx}.
// Q,K in [B*NH,S,HS] bf16; V pre-transposed [B*NH,HS,S] bf16.
// K/Vt staged UNPADDED (stride 64 = m97's GEMM read pattern, conflict-benign)
// via global_load_lds width=16 -> no VGPR round-trip, no ds_write staging.
// ---------------------------------------------------------------------------
#define PPAD_ 72  // P row stride (wave-private; 16B-aligned b128 reads)

__global__ __launch_bounds__(256) void attn_mfma(
    const short* __restrict__ Q, const short* __restrict__ K,
    const short* __restrict__ VT, short* __restrict__ O)
{
    __shared__ short Ks[64 * 64];        // [key][d]   8 KB
    __shared__ short Vt[64 * 64];        // [d][key]   8 KB
    __shared__ short Pl[4][32 * PPAD_];  // per-wave P [qrow][key]

    const int tid  = threadIdx.x;
    const int w    = tid >> 6;
    const int lane = tid & 63;
    const int l15  = lane & 15;
    const int q4   = lane >> 4;
    const int bh   = blockIdx.y;
    const size_t base = (size_t)bh * S_ * HS_;
    const int b = bh >> 4;
    const int h = bh & 15;
    const float SC = 0.125f * 1.44269504f;  // (1/sqrt(HS)) * log2(e)

    #pragma unroll 1
    for (int pass = 0; pass < 2; ++pass) {
        const int qt = pass ? (15 - blockIdx.x) : blockIdx.x;

        bf16x8 aQ[2][2];
        #pragma unroll
        for (int mi = 0; mi < 2; ++mi) {
            const int qrow = qt * 128 + w * 32 + mi * 16 + l15;
            #pragma unroll
            for (int kh = 0; kh < 2; ++kh)
                aQ[mi][kh] = *(const bf16x8*)(Q + base + (size_t)qrow * HS_ + kh * 32 + q4 * 8);
        }

        f32x4 accO[2][4];
        float l_p[2][4];
        #pragma unroll
        for (int mi = 0; mi < 2; ++mi) {
            #pragma unroll
            for (int db = 0; db < 4; ++db) accO[mi][db] = (f32x4){0.f, 0.f, 0.f, 0.f};
            #pragma unroll
            for (int r = 0; r < 4; ++r) l_p[mi][r] = 0.f;
        }

        const int ktmax = 2 * qt + 1;
        for (int kt = 0; kt <= ktmax; ++kt) {
            __syncthreads();
            // stage K [key][d] and Vt [d][key] via async global->LDS DMA
            #pragma unroll
            for (int t = 0; t < 2; ++t) {
                const int ob = t * 4096 + w * 1024;   // wave-uniform byte base
                const int c  = (ob >> 4) + lane;      // 16B-chunk index 0..511
                const int r  = c >> 3;                // row 0..63
                const int e8 = (c & 7) * 8;           // element offset in row
                gl_lds16(K + base + (size_t)(kt * 64 + r) * HS_ + e8, (char*)Ks + ob);
                gl_lds16(VT + base + (size_t)r * S_ + kt * 64 + e8, (char*)Vt + ob);
            }
            __syncthreads();

            // S = Q @ K^T
            f32x4 sb[2][4];
            #pragma unroll
            for (int nb = 0; nb < 4; ++nb) {
                const short* kr = &Ks[(nb * 16 + l15) * 64 + q4 * 8];
                bf16x8 b0 = *(const bf16x8*)(kr);
                bf16x8 b1 = *(const bf16x8*)(kr + 32);
                #pragma unroll
                for (int mi = 0; mi < 2; ++mi) {
                    f32x4 a = (f32x4){0.f, 0.f, 0.f, 0.f};
                    a = __builtin_amdgcn_mfma_f32_16x16x32_bf16(aQ[mi][0], b0, a, 0, 0, 0);
                    a = __builtin_amdgcn_mfma_f32_16x16x32_bf16(aQ[mi][1], b1, a, 0, 0, 0);
                    sb[mi][nb] = a;
                }
            }

            const bool need_mask = (kt >= 2 * qt);  // wave-uniform
            #pragma unroll
            for (int mi = 0; mi < 2; ++mi) {
                const int qb0 = qt * 128 + w * 32 + mi * 16 + q4 * 4;
                if (need_mask) {
                    #pragma unroll
                    for (int nb = 0; nb < 4; ++nb) {
                        const int kj = kt * 64 + nb * 16 + l15;
                        #pragma unroll
                        for (int r = 0; r < 4; ++r)
                            if (kj > qb0 + r) sb[mi][nb][r] = -INFINITY;
                    }
                }
                // p = exp2(s * SC); no max subtraction (bounded scores)
                short* pw = &Pl[w][0];
                #pragma unroll
                for (int nb = 0; nb < 4; ++nb) {
                    #pragma unroll
                    for (int r = 0; r < 4; ++r) {
                        const float p = exp2f(sb[mi][nb][r] * SC);
                        l_p[mi][r] += p;
                        pw[(mi * 16 + q4 * 4 + r) * PPAD_ + nb * 16 + l15] = f2bf(p);
                    }
                }
            }

            // O += P @ V
            bf16x8 aP[2][2];
            #pragma unroll
            for (int mi = 0; mi < 2; ++mi)
                #pragma unroll
                for (int kh = 0; kh < 2; ++kh)
                    aP[mi][kh] = *(const bf16x8*)(&Pl[w][(mi * 16 + l15) * PPAD_ + kh * 32 + q4 * 8]);
            #pragma unroll
            for (int db = 0; db < 4; ++db) {
                const short* vr = &Vt[(db * 16 + l15) * 64 + q4 * 8];
                bf16x8 b0 = *(const bf16x8*)(vr);
                bf16x8 b1 = *(const bf16x8*)(vr + 32);
                #pragma unroll
                for (int mi = 0; mi < 2; ++mi) {
                    accO[mi][db] = __builtin_amdgcn_mfma_f32_16x16x32_bf16(aP[mi][0], b0, accO[mi][db], 0, 0, 0);
                    accO[mi][db] = __builtin_amdgcn_mfma_f32_16x16x32_bf16(aP[mi][1], b1, accO[mi][db], 0, 0, 0);
                }
            }
        }

        // epilogue: reduce l across the 16-lane column group, write bf16 ctx
        #pragma unroll
        for (int mi = 0; mi < 2; ++mi) {
            #pragma unroll
            for (int r = 0; r < 4; ++r) {
                float ls = l_p[mi][r];
                ls += __shfl_xor(ls, 1);
                ls += __shfl_xor(ls, 2);
                ls += __shfl_xor(ls, 4);
                ls += __shfl_xor(ls, 8);
                const float inv = 1.f / ls;
                const int orow = qt * 128 + w * 32 + mi * 16 + q4 * 4 + r;
                short* op = O + ((size_t)(b * S_ + orow)) * H_ + h * HS_;
                #pragma unroll
                for (int db = 0; db < 4; ++db)
                    op[db * 16 + l15] = f2bf(accO[mi][db][r] * inv);
            }
        }
        __syncthreads();  // LDS reuse across passes
    }
}

// ---------------------------------------------------------------------------
extern "C" void kernel_launch(void* const* d_in, const int* in_sizes, int n_in,
                              void* d_out, int out_size, void* d_ws, size_t ws_size,
                              hipStream_t stream)
{
    const float* query = (const float*)d_in[0];
    const float* key   = (const float*)d_in[1];
    const float* value = (const float*)d_in[2];
    // d_in[3] = causal_mask: unused (causality computed from indices)
    const float* Wq = (const float*)d_in[4];
    const float* bq = (const float*)d_in[5];
    const float* Wk = (const float*)d_in[6];
    const float* bk = (const float*)d_in[7];
    const float* Wv = (const float*)d_in[8];
    const float* bv = (const float*)d_in[9];
    const float* Wo = (const float*)d_in[10];
    const float* bo = (const float*)d_in[11];
    float* out = (float*)d_out;

    const size_t EA = (size_t)B_ * S_ * H_;   // 8388608 activation elems
    const size_t EW = (size_t)H_ * H_;        // 1048576 weight elems

    short* Aq  = (short*)d_ws;        // bf16 inputs [M,K]
    short* Ak  = Aq  + EA;
    short* Av  = Ak  + EA;
    short* Wqb = Av  + EA;            // bf16 weights [N,K]
    short* Wkb = Wqb + EW;
    short* Wvb = Wkb + EW;
    short* Wob = Wvb + EW;
    short* qb  = Wob + EW;            // bf16 q/k [B*NH, S, HS]
    short* kb  = qb  + EA;
    short* vtb = kb  + EA;            // bf16 v TRANSPOSED [B*NH, HS, S]
    short* cb  = vtb + EA;            // bf16 ctx [B, S, H]

    const int M = B_ * S_;   // 8192

    cvt_all_k<<<dim3((int)(EA / 8 / 256), 7), 256, 0, stream>>>(
        query, key, value, Wq, Wk, Wv, Wo,
        Aq, Ak, Av, Wqb, Wkb, Wvb, Wob);

    gemm_proj_k<<<dim3(M / 128, H_ / 128, 3), 256, 0, stream>>>(
        Aq, Wqb, bq, qb, Ak, Wkb, bk, kb, Wvb, Av, bv, vtb);

    attn_mfma<<<dim3(S_ / 256, B_ * NH_), 256, 0, stream>>>(qb, kb, vtb, cb);

    gemm_out_k<<<dim3(M / 128, H_ / 128), 256, 0, stream>>>(cb, Wob, bo, out);
}

// Round 7
// 375.811 us; speedup vs baseline: 1.0627x; 1.0627x over previous
//
#include <hip/hip_runtime.h>
#include <hip/hip_bf16.h>
#include <math.h>

// Problem constants (B,S,H,NH,HS) = (4,2048,1024,16,64)
#define B_  4
#define S_  2048
#define H_  1024
#define NH_ 16
#define HS_ 64

typedef __attribute__((ext_vector_type(8))) short bf16x8;
typedef __attribute__((ext_vector_type(4))) float f32x4;

__device__ __forceinline__ short f2bf(float f) {
    // round-to-nearest-even fp32 -> bf16 (finite inputs only)
    unsigned u = __builtin_bit_cast(unsigned, f);
    u += 0x7FFFu + ((u >> 16) & 1u);
    return (short)(u >> 16);
}

typedef __attribute__((address_space(3))) void lds_void;
typedef const __attribute__((address_space(1))) void g_void;
__device__ __forceinline__ void gl_lds16(const void* g, void* l) {
    __builtin_amdgcn_global_load_lds((g_void*)g, (lds_void*)l, 16, 0, 0);
}

// XOR-swizzled LDS layout for 128 B row stride (8 x 16B chunks per row):
//   physical_chunk = logical_chunk ^ (row & 7)
// Writes: global_load_lds dest is contiguous (wave base + lane*16), so the
// SOURCE address selects chunk c ^ (r&7). Reads: lane (l15,q4) wants logical
// chunk kh*4+q4 of row ..+l15 -> physical (kh*4+q4)^(l15&7). Quarter-wave
// then hits 8 distinct banks-groups (2-way aliasing = free) instead of a
// 16-way single-bank pileup (the round-6 regression).

// ---------------------------------------------------------------------------
// Fused fp32 -> bf16 convert for all 7 tensors. blockIdx.y selects tensor.
// ---------------------------------------------------------------------------
__global__ __launch_bounds__(256) void cvt_all_k(
    const float* __restrict__ a0, const float* __restrict__ a1,
    const float* __restrict__ a2, const float* __restrict__ w0,
    const float* __restrict__ w1, const float* __restrict__ w2,
    const float* __restrict__ w3,
    short* o0, short* o1, short* o2, short* o3, short* o4, short* o5, short* o6)
{
    const int y = blockIdx.y;
    const float* ins[7]  = {a0, a1, a2, w0, w1, w2, w3};
    short*       outs[7] = {o0, o1, o2, o3, o4, o5, o6};
    const int n8 = (y < 3) ? (int)((size_t)B_ * S_ * H_ / 8) : (int)((size_t)H_ * H_ / 8);
    const int i = blockIdx.x * 256 + threadIdx.x;
    if (i >= n8) return;
    const float4* p = (const float4*)ins[y] + (size_t)i * 2;
    float4 a = p[0], b = p[1];
    bf16x8 o;
    o[0] = f2bf(a.x); o[1] = f2bf(a.y); o[2] = f2bf(a.z); o[3] = f2bf(a.w);
    o[4] = f2bf(b.x); o[5] = f2bf(b.y); o[6] = f2bf(b.z); o[7] = f2bf(b.w);
    *(bf16x8*)(outs[y] + (size_t)i * 8) = o;
}

// ---------------------------------------------------------------------------
// Shared MFMA GEMM core: 128x128 tile, BK=64 (16 iters), 4 waves (2x2),
// wave = 64x64, K fixed at 1024. LDS 16 KB per matrix, global_load_lds
// width=16, XOR-swizzled chunks (see above).
// ---------------------------------------------------------------------------
__device__ __forceinline__ void gemm_core(
    const short* __restrict__ A, const short* __restrict__ W,
    int m0, int n0, short* As, short* Ws, f32x4 acc[4][4])
{
    const int tid  = threadIdx.x;
    const int w    = tid >> 6;
    const int lane = tid & 63;
    const int l15  = lane & 15;
    const int q4   = lane >> 4;
    const int wm   = w >> 1;
    const int wn   = w & 1;
    const int K    = 1024;
    const int swz  = l15 & 7;

    const char* Abase = (const char*)A + (size_t)m0 * K * 2;
    const char* Wbase = (const char*)W + (size_t)n0 * K * 2;

    #pragma unroll
    for (int mi = 0; mi < 4; ++mi)
        #pragma unroll
        for (int ni = 0; ni < 4; ++ni)
            acc[mi][ni] = (f32x4){0.f, 0.f, 0.f, 0.f};

    for (int k0 = 0; k0 < K; k0 += 64) {
        __syncthreads();
        #pragma unroll
        for (int t = 0; t < 4; ++t) {
            const int ob  = t * 4096 + w * 1024;      // wave-uniform LDS base
            const int idx = t * 256 + w * 64 + lane;  // 16B-chunk 0..1023
            const int row = idx >> 3;
            const int sc  = (idx & 7) ^ (row & 7);    // swizzled source chunk
            gl_lds16(Abase + (size_t)row * (K * 2) + k0 * 2 + sc * 16, (char*)As + ob);
            gl_lds16(Wbase + (size_t)row * (K * 2) + k0 * 2 + sc * 16, (char*)Ws + ob);
        }
        __syncthreads();

        #pragma unroll
        for (int kh = 0; kh < 2; ++kh) {
            bf16x8 af[4], bf[4];
            #pragma unroll
            for (int mi = 0; mi < 4; ++mi)
                af[mi] = *(const bf16x8*)(As + (wm * 64 + mi * 16 + l15) * 64
                                             + (((kh * 4 + q4) ^ swz) * 8));
            #pragma unroll
            for (int ni = 0; ni < 4; ++ni)
                bf[ni] = *(const bf16x8*)(Ws + (wn * 64 + ni * 16 + l15) * 64
                                             + (((kh * 4 + q4) ^ swz) * 8));
            #pragma unroll
            for (int mi = 0; mi < 4; ++mi)
                #pragma unroll
                for (int ni = 0; ni < 4; ++ni)
                    acc[mi][ni] = __builtin_amdgcn_mfma_f32_16x16x32_bf16(
                        af[mi], bf[ni], acc[mi][ni], 0, 0, 0);
        }
    }
}

// ---------------------------------------------------------------------------
// Fused projection GEMMs: z=0 -> q (scatter [B*NH,S,HS]), z=1 -> k (same),
// z=2 -> vT = Wv @ value^T (transpose-scatter [B*NH,HS,S]; bx/by roles swap).
// ---------------------------------------------------------------------------
__global__ __launch_bounds__(256) void gemm_proj_k(
    const short* __restrict__ Aq, const short* __restrict__ Wqb,
    const float* __restrict__ bq, short* __restrict__ qb,
    const short* __restrict__ Ak, const short* __restrict__ Wkb,
    const float* __restrict__ bk, short* __restrict__ kb,
    const short* __restrict__ Wvb, const short* __restrict__ Av,
    const float* __restrict__ bv, short* __restrict__ vtb)
{
    __shared__ short As[128 * 64];   // 16 KB
    __shared__ short Ws[128 * 64];   // 16 KB

    const int z = blockIdx.z;
    const short *A, *W; const float* bias; short* out;
    if (z == 0)      { A = Aq;  W = Wqb; bias = bq; out = qb;  }
    else if (z == 1) { A = Ak;  W = Wkb; bias = bk; out = kb;  }
    else             { A = Wvb; W = Av;  bias = bv; out = vtb; }
    const int m0 = (z == 2 ? blockIdx.y : blockIdx.x) * 128;
    const int n0 = (z == 2 ? blockIdx.x : blockIdx.y) * 128;

    f32x4 acc[4][4];
    gemm_core(A, W, m0, n0, As, Ws, acc);

    const int tid  = threadIdx.x;
    const int w    = tid >> 6;
    const int lane = tid & 63;
    const int l15  = lane & 15;
    const int q4   = lane >> 4;
    const int wm   = w >> 1;
    const int wn   = w & 1;

    #pragma unroll
    for (int mi = 0; mi < 4; ++mi) {
        #pragma unroll
        for (int r = 0; r < 4; ++r) {
            const int m = m0 + wm * 64 + mi * 16 + q4 * 4 + r;
            #pragma unroll
            for (int ni = 0; ni < 4; ++ni) {
                const int n = n0 + wn * 64 + ni * 16 + l15;
                const float v = acc[mi][ni][r] + bias[z == 2 ? m : n];
                if (z != 2) {
                    const int b = m >> 11, s = m & (S_ - 1);
                    const int h = n >> 6,  d = n & (HS_ - 1);
                    out[(((size_t)b * NH_ + h) * S_ + s) * HS_ + d] = f2bf(v);
                } else {
                    const int b = n >> 11, s = n & (S_ - 1);
                    const int h = m >> 6,  d = m & (HS_ - 1);
                    out[(((size_t)b * NH_ + h) * HS_ + d) * S_ + s] = f2bf(v);
                }
            }
        }
    }
}

// ---------------------------------------------------------------------------
// Output-projection GEMM: fp32 row-major out = ctx @ Wo^T + bo
// ---------------------------------------------------------------------------
__global__ __launch_bounds__(256) void gemm_out_k(
    const short* __restrict__ A, const short* __restrict__ W,
    const float* __restrict__ bias, float* __restrict__ Cout)
{
    __shared__ short As[128 * 64];
    __shared__ short Ws[128 * 64];
    const int m0 = blockIdx.x * 128;
    const int n0 = blockIdx.y * 128;

    f32x4 acc[4][4];
    gemm_core(A, W, m0, n0, As, Ws, acc);

    const int tid  = threadIdx.x;
    const int w    = tid >> 6;
    const int lane = tid & 63;
    const int l15  = lane & 15;
    const int q4   = lane >> 4;
    const int wm   = w >> 1;
    const int wn   = w & 1;

    #pragma unroll
    for (int mi = 0; mi < 4; ++mi)
        #pragma unroll
        for (int r = 0; r < 4; ++r) {
            const int m = m0 + wm * 64 + mi * 16 + q4 * 4 + r;
            #pragma unroll
            for (int ni = 0; ni < 4; ++ni) {
                const int n = n0 + wn * 64 + ni * 16 + l15;
                Cout[(size_t)m * H_ + n] = acc[mi][ni][r] + bias[n];
            }
        }
}

// ---------------------------------------------------------------------------
// MFMA flash attention, no-max softmax, work-balanced pairing {bx, 15-bx}.
// Q,K in [B*NH,S,HS] bf16; V pre-transposed [B*NH,HS,S] bf16.
// K/Vt staged via global_load_lds width=16 into XOR-swizzled 128 B rows
// (fixes the round-6 16-way conflicts while keeping async DMA staging).
// ---------------------------------------------------------------------------
#define PPAD_ 72  // P row stride (wave-private; 16B-aligned b128 reads)

__global__ __launch_bounds__(256) void attn_mfma(
    const short* __restrict__ Q, const short* __restrict__ K,
    const short* __restrict__ VT, short* __restrict__ O)
{
    __shared__ short Ks[64 * 64];        // [key][d]   8 KB, swizzled
    __shared__ short Vt[64 * 64];        // [d][key]   8 KB, swizzled
    __shared__ short Pl[4][32 * PPAD_];  // per-wave P [qrow][key]

    const int tid  = threadIdx.x;
    const int w    = tid >> 6;
    const int lane = tid & 63;
    const int l15  = lane & 15;
    const int q4   = lane >> 4;
    const int swz  = l15 & 7;
    const int bh   = blockIdx.y;
    const size_t base = (size_t)bh * S_ * HS_;
    const int b = bh >> 4;
    const int h = bh & 15;
    const float SC = 0.125f * 1.44269504f;  // (1/sqrt(HS)) * log2(e)

    #pragma unroll 1
    for (int pass = 0; pass < 2; ++pass) {
        const int qt = pass ? (15 - blockIdx.x) : blockIdx.x;

        bf16x8 aQ[2][2];
        #pragma unroll
        for (int mi = 0; mi < 2; ++mi) {
            const int qrow = qt * 128 + w * 32 + mi * 16 + l15;
            #pragma unroll
            for (int kh = 0; kh < 2; ++kh)
                aQ[mi][kh] = *(const bf16x8*)(Q + base + (size_t)qrow * HS_ + kh * 32 + q4 * 8);
        }

        f32x4 accO[2][4];
        float l_p[2][4];
        #pragma unroll
        for (int mi = 0; mi < 2; ++mi) {
            #pragma unroll
            for (int db = 0; db < 4; ++db) accO[mi][db] = (f32x4){0.f, 0.f, 0.f, 0.f};
            #pragma unroll
            for (int r = 0; r < 4; ++r) l_p[mi][r] = 0.f;
        }

        const int ktmax = 2 * qt + 1;
        for (int kt = 0; kt <= ktmax; ++kt) {
            __syncthreads();
            // stage K [key][d] and Vt [d][key] via async DMA, swizzled source
            #pragma unroll
            for (int t = 0; t < 2; ++t) {
                const int ob  = t * 4096 + w * 1024;      // wave-uniform base
                const int idx = t * 256 + w * 64 + lane;  // 16B-chunk 0..511
                const int r   = idx >> 3;
                const int sc  = (idx & 7) ^ (r & 7);      // swizzled src chunk
                gl_lds16(K + base + (size_t)(kt * 64 + r) * HS_ + sc * 8, (char*)Ks + ob);
                gl_lds16(VT + base + (size_t)r * S_ + kt * 64 + sc * 8, (char*)Vt + ob);
            }
            __syncthreads();

            // S = Q @ K^T
            f32x4 sb[2][4];
            #pragma unroll
            for (int nb = 0; nb < 4; ++nb) {
                const short* krow = &Ks[(nb * 16 + l15) * 64];
                bf16x8 b0 = *(const bf16x8*)(krow + ((q4 ^ swz) * 8));
                bf16x8 b1 = *(const bf16x8*)(krow + (((4 + q4) ^ swz) * 8));
                #pragma unroll
                for (int mi = 0; mi < 2; ++mi) {
                    f32x4 a = (f32x4){0.f, 0.f, 0.f, 0.f};
                    a = __builtin_amdgcn_mfma_f32_16x16x32_bf16(aQ[mi][0], b0, a, 0, 0, 0);
                    a = __builtin_amdgcn_mfma_f32_16x16x32_bf16(aQ[mi][1], b1, a, 0, 0, 0);
                    sb[mi][nb] = a;
                }
            }

            const bool need_mask = (kt >= 2 * qt);  // wave-uniform
            #pragma unroll
            for (int mi = 0; mi < 2; ++mi) {
                const int qb0 = qt * 128 + w * 32 + mi * 16 + q4 * 4;
                if (need_mask) {
                    #pragma unroll
                    for (int nb = 0; nb < 4; ++nb) {
                        const int kj = kt * 64 + nb * 16 + l15;
                        #pragma unroll
                        for (int r = 0; r < 4; ++r)
                            if (kj > qb0 + r) sb[mi][nb][r] = -INFINITY;
                    }
                }
                // p = exp2(s * SC); no max subtraction (bounded scores)
                short* pw = &Pl[w][0];
                #pragma unroll
                for (int nb = 0; nb < 4; ++nb) {
                    #pragma unroll
                    for (int r = 0; r < 4; ++r) {
                        const float p = exp2f(sb[mi][nb][r] * SC);
                        l_p[mi][r] += p;
                        pw[(mi * 16 + q4 * 4 + r) * PPAD_ + nb * 16 + l15] = f2bf(p);
                    }
                }
            }

            // O += P @ V
            bf16x8 aP[2][2];
            #pragma unroll
            for (int mi = 0; mi < 2; ++mi)
                #pragma unroll
                for (int kh = 0; kh < 2; ++kh)
                    aP[mi][kh] = *(const bf16x8*)(&Pl[w][(mi * 16 + l15) * PPAD_ + kh * 32 + q4 * 8]);
            #pragma unroll
            for (int db = 0; db < 4; ++db) {
                const short* vrow = &Vt[(db * 16 + l15) * 64];
                bf16x8 b0 = *(const bf16x8*)(vrow + ((q4 ^ swz) * 8));
                bf16x8 b1 = *(const bf16x8*)(vrow + (((4 + q4) ^ swz) * 8));
                #pragma unroll
                for (int mi = 0; mi < 2; ++mi) {
                    accO[mi][db] = __builtin_amdgcn_mfma_f32_16x16x32_bf16(aP[mi][0], b0, accO[mi][db], 0, 0, 0);
                    accO[mi][db] = __builtin_amdgcn_mfma_f32_16x16x32_bf16(aP[mi][1], b1, accO[mi][db], 0, 0, 0);
                }
            }
        }

        // epilogue: reduce l across the 16-lane column group, write bf16 ctx
        #pragma unroll
        for (int mi = 0; mi < 2; ++mi) {
            #pragma unroll
            for (int r = 0; r < 4; ++r) {
                float ls = l_p[mi][r];
                ls += __shfl_xor(ls, 1);
                ls += __shfl_xor(ls, 2);
                ls += __shfl_xor(ls, 4);
                ls += __shfl_xor(ls, 8);
                const float inv = 1.f / ls;
                const int orow = qt * 128 + w * 32 + mi * 16 + q4 * 4 + r;
                short* op = O + ((size_t)(b * S_ + orow)) * H_ + h * HS_;
                #pragma unroll
                for (int db = 0; db < 4; ++db)
                    op[db * 16 + l15] = f2bf(accO[mi][db][r] * inv);
            }
        }
        __syncthreads();  // LDS reuse across passes
    }
}

// ---------------------------------------------------------------------------
extern "C" void kernel_launch(void* const* d_in, const int* in_sizes, int n_in,
                              void* d_out, int out_size, void* d_ws, size_t ws_size,
                              hipStream_t stream)
{
    const float* query = (const float*)d_in[0];
    const float* key   = (const float*)d_in[1];
    const float* value = (const float*)d_in[2];
    // d_in[3] = causal_mask: unused (causality computed from indices)
    const float* Wq = (const float*)d_in[4];
    const float* bq = (const float*)d_in[5];
    const float* Wk = (const float*)d_in[6];
    const float* bk = (const float*)d_in[7];
    const float* Wv = (const float*)d_in[8];
    const float* bv = (const float*)d_in[9];
    const float* Wo = (const float*)d_in[10];
    const float* bo = (const float*)d_in[11];
    float* out = (float*)d_out;

    const size_t EA = (size_t)B_ * S_ * H_;   // 8388608 activation elems
    const size_t EW = (size_t)H_ * H_;        // 1048576 weight elems

    short* Aq  = (short*)d_ws;        // bf16 inputs [M,K]
    short* Ak  = Aq  + EA;
    short* Av  = Ak  + EA;
    short* Wqb = Av  + EA;            // bf16 weights [N,K]
    short* Wkb = Wqb + EW;
    short* Wvb = Wkb + EW;
    short* Wob = Wvb + EW;
    short* qb  = Wob + EW;            // bf16 q/k [B*NH, S, HS]
    short* kb  = qb  + EA;
    short* vtb = kb  + EA;            // bf16 v TRANSPOSED [B*NH, HS, S]
    short* cb  = vtb + EA;            // bf16 ctx [B, S, H]

    const int M = B_ * S_;   // 8192

    cvt_all_k<<<dim3((int)(EA / 8 / 256), 7), 256, 0, stream>>>(
        query, key, value, Wq, Wk, Wv, Wo,
        Aq, Ak, Av, Wqb, Wkb, Wvb, Wob);

    gemm_proj_k<<<dim3(M / 128, H_ / 128, 3), 256, 0, stream>>>(
        Aq, Wqb, bq, qb, Ak, Wkb, bk, kb, Wvb, Av, bv, vtb);

    attn_mfma<<<dim3(S_ / 256, B_ * NH_), 256, 0, stream>>>(qb, kb, vtb, cb);

    gemm_out_k<<<dim3(M / 128, H_ / 128), 256, 0, stream>>>(cb, Wob, bo, out);
}